// Round 3
// baseline (278.989 us; speedup 1.0000x reference)
//
#include <hip/hip_runtime.h>

#define POOL 7
#define CCH  256   // channels (C)

typedef float f32x4 __attribute__((ext_vector_type(4)));

// ---------- pass 0: zero the per-level counters in ws ----------
__global__ void zero_counters(int* __restrict__ cnt) {
    if (threadIdx.x < 4) cnt[threadIdx.x] = 0;
}

// ---------- pass 1: bucket boxes by FPN level ----------
__global__ void bucket_boxes(const float* __restrict__ boxes,
                             const int*   __restrict__ image_shape,
                             int M,
                             int* __restrict__ cnt,      // [4]
                             int* __restrict__ lists)    // [4][M]
{
    const int m = blockIdx.x * blockDim.x + threadIdx.x;
    if (m >= M) return;
    const float y1 = boxes[m * 4 + 0];
    const float x1 = boxes[m * 4 + 1];
    const float y2 = boxes[m * 4 + 2];
    const float x2 = boxes[m * 4 + 3];
    const float h  = y2 - y1;
    const float w  = x2 - x1;
    const float area = (float)(image_shape[0] * image_shape[1]);
    // lvl = clip(4 + round(log2(sqrt(w*h)*sqrt(area)/224)), 2, 5); jnp.round == rintf
    const float lvlf = logf(sqrtf(w * h) * sqrtf(area) / 224.0f) * 1.4426950408889634f;
    const int lvl = (int)fminf(fmaxf(4.0f + rintf(lvlf), 2.0f), 5.0f);
    const int l = lvl - 2;
    const int idx = atomicAdd(&cnt[l], 1);
    lists[l * M + idx] = m;
    (void)x1;
}

// ---------- pass 2: one block (4 waves) per box, level-grouped ----------
__global__ __launch_bounds__(256) void roialign_boxes(
    const float* __restrict__ boxes,       // [M, 4]
    const float* __restrict__ feat2,       // [B,256,256,C]
    const float* __restrict__ feat3,
    const float* __restrict__ feat4,
    const float* __restrict__ feat5,
    const int*   __restrict__ cnt,         // [4]
    const int*   __restrict__ lists,       // [4][M]
    float*       __restrict__ out,         // [M, P, P, C]
    int M, int N)
{
    const int P = POOL;
    const int j = blockIdx.x;

    // locate (level, slot) for this block
    const int c0 = cnt[0], c1 = cnt[1], c2 = cnt[2];
    int l, r = j;
    if (j < c0)               { l = 0; }
    else if (j < c0 + c1)     { l = 1; r = j - c0; }
    else if (j < c0 + c1 + c2){ l = 2; r = j - c0 - c1; }
    else                      { l = 3; r = j - c0 - c1 - c2; }
    const int m = lists[l * M + r];
    const int b = m / N;

    const float* feat;
    switch (l) {
        case 0:  feat = feat2; break;
        case 1:  feat = feat3; break;
        case 2:  feat = feat4; break;
        default: feat = feat5; break;
    }
    const int H = 256 >> l;
    const int W = H;

    const float y1 = boxes[m * 4 + 0];
    const float x1 = boxes[m * 4 + 1];
    const float y2 = boxes[m * 4 + 2];
    const float x2 = boxes[m * 4 + 3];
    const float h  = y2 - y1;
    const float w  = x2 - x1;

    const int wave = threadIdx.x >> 6;
    const int lane = threadIdx.x & 63;
    const int c    = lane * 4;             // C == 256 -> 64 lanes * 4

    const float* __restrict__ fb = feat + (size_t)b * ((size_t)H * W * CCH);
    float* __restrict__ obox = out + (size_t)m * (P * P) * CCH + c;

    const float ybase = y1 * (float)(H - 1);
    const float ystep = h * (float)(H - 1) / (float)(P - 1);
    const float xbase = x1 * (float)(W - 1);
    const float xstep = w * (float)(W - 1) / (float)(P - 1);

    for (int py = wave; py < P; py += 4) {
        const float sy  = ybase + (float)py * ystep;
        const float y0f = floorf(sy);
        const float fy  = sy - y0f;
        int yi0 = (int)y0f;
        yi0 = yi0 < 0 ? 0 : (yi0 > H - 1 ? H - 1 : yi0);
        const int yi1 = yi0 + 1 > H - 1 ? H - 1 : yi0 + 1;
        const bool vy = (sy >= 0.0f) && (sy <= (float)(H - 1));
        const float gy = 1.0f - fy;

        const float* __restrict__ row0 = fb + (size_t)yi0 * W * CCH + c;
        const float* __restrict__ row1 = fb + (size_t)yi1 * W * CCH + c;
        float* __restrict__ orow = obox + (size_t)py * P * CCH;

#pragma unroll
        for (int px = 0; px < P; ++px) {
            const float sx  = xbase + (float)px * xstep;
            const float x0f = floorf(sx);
            const float fx  = sx - x0f;
            int xi0 = (int)x0f;
            xi0 = xi0 < 0 ? 0 : (xi0 > W - 1 ? W - 1 : xi0);
            const int xi1 = xi0 + 1 > W - 1 ? W - 1 : xi0 + 1;
            const bool valid = vy && (sx >= 0.0f) && (sx <= (float)(W - 1));

            const f32x4 v00 = *(const f32x4*)(row0 + xi0 * CCH);
            const f32x4 v01 = *(const f32x4*)(row0 + xi1 * CCH);
            const f32x4 v10 = *(const f32x4*)(row1 + xi0 * CCH);
            const f32x4 v11 = *(const f32x4*)(row1 + xi1 * CCH);

            const float gx = 1.0f - fx;
            f32x4 rv = (v00 * gx + v01 * fx) * gy + (v10 * gx + v11 * fx) * fy;
            rv *= (valid ? 1.0f : 0.0f);

            __builtin_nontemporal_store(rv, (f32x4*)(orow + px * CCH));
        }
    }
}

extern "C" void kernel_launch(void* const* d_in, const int* in_sizes, int n_in,
                              void* d_out, int out_size, void* d_ws, size_t ws_size,
                              hipStream_t stream) {
    const float* boxes       = (const float*)d_in[0];  // [B, N, 4]
    const int*   image_shape = (const int*)  d_in[1];  // [3]
    const float* feat2       = (const float*)d_in[2];
    const float* feat3       = (const float*)d_in[3];
    const float* feat4       = (const float*)d_in[4];
    const float* feat5       = (const float*)d_in[5];
    float*       out         = (float*)d_out;

    const int B = 2;
    const int N = in_sizes[0] / (B * 4);               // 1000
    const int M = B * N;                               // 2000 boxes

    int* cnt   = (int*)d_ws;                           // [4]
    int* lists = (int*)d_ws + 8;                       // [4][M] (8-int pad for alignment)

    zero_counters<<<1, 64, 0, stream>>>(cnt);
    bucket_boxes<<<(M + 255) / 256, 256, 0, stream>>>(boxes, image_shape, M, cnt, lists);
    roialign_boxes<<<M, 256, 0, stream>>>(boxes, feat2, feat3, feat4, feat5,
                                          cnt, lists, out, M, N);
}

// Round 4
// 272.192 us; speedup vs baseline: 1.0250x; 1.0250x over previous
//
#include <hip/hip_runtime.h>

#define POOL   7
#define CCH    256   // channels (C)
#define NBANDS 16
#define NBUCK  (2 * 4 * NBANDS)   // batch x level x y-band

typedef float f32x4 __attribute__((ext_vector_type(4)));

// ---------- pass 1: single-block counting sort of boxes by (batch, level, y-band) ----------
// Writes sorted[i] = m | (level_idx << 28). Order within a bucket is arbitrary
// (atomic cursor), which is fine: each box writes a disjoint output slab.
__global__ __launch_bounds__(1024) void sort_boxes(
    const float* __restrict__ boxes,       // [M,4]
    const int*   __restrict__ image_shape, // [3]
    int M, int N,
    int* __restrict__ sorted)              // [M]
{
    __shared__ int hist[NBUCK];
    __shared__ int base[NBUCK];
    const int t = threadIdx.x;
    if (t < NBUCK) hist[t] = 0;
    __syncthreads();

    const float area = (float)(image_shape[0] * image_shape[1]);

    int keys[2], ms[2], nloc = 0;
    for (int m = t; m < M; m += 1024) {
        const float y1 = boxes[m * 4 + 0];
        const float y2 = boxes[m * 4 + 2];
        const float x1 = boxes[m * 4 + 1];
        const float x2 = boxes[m * 4 + 3];
        const float h = y2 - y1, w = x2 - x1;
        // lvl = clip(4 + round(log2(sqrt(w*h)*sqrt(area)/224)), 2, 5); jnp.round == rintf
        const float lvlf = logf(sqrtf(w * h) * sqrtf(area) / 224.0f) * 1.4426950408889634f;
        const int lvl = (int)fminf(fmaxf(4.0f + rintf(lvlf), 2.0f), 5.0f);
        const int l = lvl - 2;
        const int b = m / N;
        int yq = (int)(0.5f * (y1 + y2) * (float)NBANDS);
        yq = yq < 0 ? 0 : (yq > NBANDS - 1 ? NBANDS - 1 : yq);
        const int key = (b * 4 + l) * NBANDS + yq;
        keys[nloc] = key;
        ms[nloc]   = m | (l << 28);
        ++nloc;
        atomicAdd(&hist[key], 1);
    }
    __syncthreads();

    if (t == 0) {
        int s = 0;
        for (int i = 0; i < NBUCK; ++i) { base[i] = s; s += hist[i]; }
    }
    __syncthreads();

    for (int i = 0; i < nloc; ++i) {
        const int pos = atomicAdd(&base[keys[i]], 1);
        sorted[pos] = ms[i];
    }
}

// ---------- pass 2: one block (4 waves) per box; XCD-chunked sorted order ----------
__global__ __launch_bounds__(256) void roialign_boxes(
    const float* __restrict__ boxes,
    const float* __restrict__ feat2,       // [B,256,256,C]
    const float* __restrict__ feat3,
    const float* __restrict__ feat4,
    const float* __restrict__ feat5,
    const int*   __restrict__ sorted,      // [M] packed m | (l<<28)
    float*       __restrict__ out,         // [M, P, P, C]
    int M, int N)
{
    const int P = POOL;

    // Bijective inverse-round-robin: dispatch assigns block i to XCD i%8; we want
    // XCD k to process a CONTIGUOUS chunk of the sorted order (m204 formula).
    const int q = M >> 3, r = M & 7;
    const int x = blockIdx.x & 7, o = blockIdx.x >> 3;
    const int basei = (x < r) ? x * (q + 1) : r * (q + 1) + (x - r) * q;
    const int sidx = basei + o;

    const int e = sorted[sidx];
    const int m = e & 0x0FFFFFFF;
    const int l = e >> 28;
    const int b = m / N;

    const float* feat;
    switch (l) {
        case 0:  feat = feat2; break;
        case 1:  feat = feat3; break;
        case 2:  feat = feat4; break;
        default: feat = feat5; break;
    }
    const int H = 256 >> l;
    const int W = H;

    const float y1 = boxes[m * 4 + 0];
    const float x1 = boxes[m * 4 + 1];
    const float y2 = boxes[m * 4 + 2];
    const float x2 = boxes[m * 4 + 3];
    const float h  = y2 - y1;
    const float w  = x2 - x1;

    const int wave = threadIdx.x >> 6;
    const int lane = threadIdx.x & 63;
    const int c    = lane * 4;             // C == 256 -> 64 lanes * 4

    const float* __restrict__ fb = feat + (size_t)b * ((size_t)H * W * CCH);
    float* __restrict__ obox = out + (size_t)m * (P * P) * CCH + c;

    const float ybase = y1 * (float)(H - 1);
    const float ystep = h * (float)(H - 1) / (float)(P - 1);
    const float xbase = x1 * (float)(W - 1);
    const float xstep = w * (float)(W - 1) / (float)(P - 1);

    for (int py = wave; py < P; py += 4) {
        const float sy  = ybase + (float)py * ystep;
        const float y0f = floorf(sy);
        const float fy  = sy - y0f;
        int yi0 = (int)y0f;
        yi0 = yi0 < 0 ? 0 : (yi0 > H - 1 ? H - 1 : yi0);
        const int yi1 = yi0 + 1 > H - 1 ? H - 1 : yi0 + 1;
        const bool vy = (sy >= 0.0f) && (sy <= (float)(H - 1));
        const float gy = 1.0f - fy;

        const float* __restrict__ row0 = fb + (size_t)yi0 * W * CCH + c;
        const float* __restrict__ row1 = fb + (size_t)yi1 * W * CCH + c;
        float* __restrict__ orow = obox + (size_t)py * P * CCH;

#pragma unroll
        for (int px = 0; px < P; ++px) {
            const float sx  = xbase + (float)px * xstep;
            const float x0f = floorf(sx);
            const float fx  = sx - x0f;
            int xi0 = (int)x0f;
            xi0 = xi0 < 0 ? 0 : (xi0 > W - 1 ? W - 1 : xi0);
            const int xi1 = xi0 + 1 > W - 1 ? W - 1 : xi0 + 1;
            const bool valid = vy && (sx >= 0.0f) && (sx <= (float)(W - 1));

            const f32x4 v00 = *(const f32x4*)(row0 + xi0 * CCH);
            const f32x4 v01 = *(const f32x4*)(row0 + xi1 * CCH);
            const f32x4 v10 = *(const f32x4*)(row1 + xi0 * CCH);
            const f32x4 v11 = *(const f32x4*)(row1 + xi1 * CCH);

            const float gx = 1.0f - fx;
            f32x4 rv = (v00 * gx + v01 * fx) * gy + (v10 * gx + v11 * fx) * fy;
            rv *= (valid ? 1.0f : 0.0f);

            __builtin_nontemporal_store(rv, (f32x4*)(orow + px * CCH));
        }
    }
}

extern "C" void kernel_launch(void* const* d_in, const int* in_sizes, int n_in,
                              void* d_out, int out_size, void* d_ws, size_t ws_size,
                              hipStream_t stream) {
    const float* boxes       = (const float*)d_in[0];  // [B, N, 4]
    const int*   image_shape = (const int*)  d_in[1];  // [3]
    const float* feat2       = (const float*)d_in[2];
    const float* feat3       = (const float*)d_in[3];
    const float* feat4       = (const float*)d_in[4];
    const float* feat5       = (const float*)d_in[5];
    float*       out         = (float*)d_out;

    const int B = 2;
    const int N = in_sizes[0] / (B * 4);               // 1000
    const int M = B * N;                               // 2000 boxes

    int* sorted = (int*)d_ws;                          // [M]

    sort_boxes<<<1, 1024, 0, stream>>>(boxes, image_shape, M, N, sorted);
    roialign_boxes<<<M, 256, 0, stream>>>(boxes, feat2, feat3, feat4, feat5,
                                          sorted, out, M, N);
}

// Round 5
// 271.516 us; speedup vs baseline: 1.0275x; 1.0025x over previous
//
#include <hip/hip_runtime.h>

#define POOL   7
#define CCH    256   // channels (C)
#define NBANDS 16
#define NBUCK  (2 * 4 * NBANDS)   // batch x level x y-band

typedef float f32x4 __attribute__((ext_vector_type(4)));

// ---------- pass 1: single-block counting sort of boxes by (batch, level, y-band) ----------
__global__ __launch_bounds__(1024) void sort_boxes(
    const float* __restrict__ boxes,       // [M,4]
    const int*   __restrict__ image_shape, // [3]
    int M, int N,
    int* __restrict__ sorted)              // [M] packed m | (l<<28)
{
    __shared__ int hist[NBUCK];
    __shared__ int base[NBUCK];
    const int t = threadIdx.x;
    if (t < NBUCK) hist[t] = 0;
    __syncthreads();

    const float area = (float)(image_shape[0] * image_shape[1]);

    int keys[2], ms[2], nloc = 0;
    for (int m = t; m < M; m += 1024) {
        const float y1 = boxes[m * 4 + 0];
        const float y2 = boxes[m * 4 + 2];
        const float x1 = boxes[m * 4 + 1];
        const float x2 = boxes[m * 4 + 3];
        const float h = y2 - y1, w = x2 - x1;
        const float lvlf = logf(sqrtf(w * h) * sqrtf(area) / 224.0f) * 1.4426950408889634f;
        const int lvl = (int)fminf(fmaxf(4.0f + rintf(lvlf), 2.0f), 5.0f);
        const int l = lvl - 2;
        const int b = m / N;
        int yq = (int)(0.5f * (y1 + y2) * (float)NBANDS);
        yq = yq < 0 ? 0 : (yq > NBANDS - 1 ? NBANDS - 1 : yq);
        const int key = (b * 4 + l) * NBANDS + yq;
        keys[nloc] = key;
        ms[nloc]   = m | (l << 28);
        ++nloc;
        atomicAdd(&hist[key], 1);
        (void)x1;
    }
    __syncthreads();

    if (t == 0) {
        int s = 0;
        for (int i = 0; i < NBUCK; ++i) { base[i] = s; s += hist[i]; }
    }
    __syncthreads();

    for (int i = 0; i < nloc; ++i) {
        const int pos = atomicAdd(&base[keys[i]], 1);
        sorted[pos] = ms[i];
    }
}

// ---------- pass 2: time-interleaved persistent blocks ----------
// Grid 1024 blocks (4/CU). XCD x = blk&7 owns a contiguous sorted range; its 128
// blocks sweep it as idx = start + t*128 + (blk>>3), so boxes ACTIVE AT THE SAME
// INSTANT are consecutive in (batch, level, y-band) order -> patches overlap ->
// per-XCD L2 serves the gathers.
__global__ __launch_bounds__(256) void roialign_boxes(
    const float* __restrict__ boxes,
    const float* __restrict__ feat2,       // [B,256,256,C]
    const float* __restrict__ feat3,
    const float* __restrict__ feat4,
    const float* __restrict__ feat5,
    const int*   __restrict__ sorted,      // [M] packed m | (l<<28)
    float*       __restrict__ out,         // [M, P, P, C]
    int M, int N)
{
    const int P = POOL;

    const int x   = blockIdx.x & 7;        // XCD id (dispatch round-robins %8)
    const int g   = blockIdx.x >> 3;       // local block on this XCD
    const int nbx = gridDim.x >> 3;        // blocks per XCD (128)

    const int q = M >> 3, r = M & 7;
    const int start = x * q + (x < r ? x : r);
    const int cnt   = q + (x < r ? 1 : 0);

    const int wave = threadIdx.x >> 6;
    const int lane = threadIdx.x & 63;
    const int c    = lane * 4;             // C == 256 -> 64 lanes * 4

    for (int idx = start + g; idx < start + cnt; idx += nbx) {
        const int e = sorted[idx];
        const int m = e & 0x0FFFFFFF;
        const int l = e >> 28;
        const int b = m / N;

        const float* feat;
        switch (l) {
            case 0:  feat = feat2; break;
            case 1:  feat = feat3; break;
            case 2:  feat = feat4; break;
            default: feat = feat5; break;
        }
        const int H = 256 >> l;
        const int W = H;

        const float y1 = boxes[m * 4 + 0];
        const float x1 = boxes[m * 4 + 1];
        const float y2 = boxes[m * 4 + 2];
        const float x2 = boxes[m * 4 + 3];
        const float h  = y2 - y1;
        const float w  = x2 - x1;

        const float* __restrict__ fb = feat + (size_t)b * ((size_t)H * W * CCH);
        float* __restrict__ obox = out + (size_t)m * (P * P) * CCH + c;

        const float ybase = y1 * (float)(H - 1);
        const float ystep = h * (float)(H - 1) / (float)(P - 1);
        const float xbase = x1 * (float)(W - 1);
        const float xstep = w * (float)(W - 1) / (float)(P - 1);

        for (int py = wave; py < P; py += 4) {
            const float sy  = ybase + (float)py * ystep;
            const float y0f = floorf(sy);
            const float fy  = sy - y0f;
            int yi0 = (int)y0f;
            yi0 = yi0 < 0 ? 0 : (yi0 > H - 1 ? H - 1 : yi0);
            const int yi1 = yi0 + 1 > H - 1 ? H - 1 : yi0 + 1;
            const bool vy = (sy >= 0.0f) && (sy <= (float)(H - 1));
            const float gy = 1.0f - fy;

            const float* __restrict__ row0 = fb + (size_t)yi0 * W * CCH + c;
            const float* __restrict__ row1 = fb + (size_t)yi1 * W * CCH + c;
            float* __restrict__ orow = obox + (size_t)py * P * CCH;

#pragma unroll
            for (int px = 0; px < P; ++px) {
                const float sx  = xbase + (float)px * xstep;
                const float x0f = floorf(sx);
                const float fx  = sx - x0f;
                int xi0 = (int)x0f;
                xi0 = xi0 < 0 ? 0 : (xi0 > W - 1 ? W - 1 : xi0);
                const int xi1 = xi0 + 1 > W - 1 ? W - 1 : xi0 + 1;
                const bool valid = vy && (sx >= 0.0f) && (sx <= (float)(W - 1));

                const f32x4 v00 = *(const f32x4*)(row0 + xi0 * CCH);
                const f32x4 v01 = *(const f32x4*)(row0 + xi1 * CCH);
                const f32x4 v10 = *(const f32x4*)(row1 + xi0 * CCH);
                const f32x4 v11 = *(const f32x4*)(row1 + xi1 * CCH);

                const float gx = 1.0f - fx;
                f32x4 rv = (v00 * gx + v01 * fx) * gy + (v10 * gx + v11 * fx) * fy;
                rv *= (valid ? 1.0f : 0.0f);

                __builtin_nontemporal_store(rv, (f32x4*)(orow + px * CCH));
            }
        }
    }
}

extern "C" void kernel_launch(void* const* d_in, const int* in_sizes, int n_in,
                              void* d_out, int out_size, void* d_ws, size_t ws_size,
                              hipStream_t stream) {
    const float* boxes       = (const float*)d_in[0];  // [B, N, 4]
    const int*   image_shape = (const int*)  d_in[1];  // [3]
    const float* feat2       = (const float*)d_in[2];
    const float* feat3       = (const float*)d_in[3];
    const float* feat4       = (const float*)d_in[4];
    const float* feat5       = (const float*)d_in[5];
    float*       out         = (float*)d_out;

    const int B = 2;
    const int N = in_sizes[0] / (B * 4);               // 1000
    const int M = B * N;                               // 2000 boxes

    int* sorted = (int*)d_ws;                          // [M]

    sort_boxes<<<1, 1024, 0, stream>>>(boxes, image_shape, M, N, sorted);
    roialign_boxes<<<1024, 256, 0, stream>>>(boxes, feat2, feat3, feat4, feat5,
                                             sorted, out, M, N);
}